// Round 13
// baseline (219.665 us; speedup 1.0000x reference)
//
#include <hip/hip_runtime.h>
#include <hip/hip_bf16.h>

// Problem constants
#define BATCH 2
#define TSEQ 2048
#define DIM 1024
#define NH 16
#define HDIM 64
#define MROWS (BATCH * TSEQ)   // 4096

typedef __attribute__((ext_vector_type(4))) float f32x4;
typedef __attribute__((ext_vector_type(8))) short short8;

__device__ __forceinline__ unsigned short f2bf(float f) {
    union { float f; unsigned int u; } x; x.f = f;
    unsigned int r = x.u + 0x7fffu + ((x.u >> 16) & 1u);
    return (unsigned short)(r >> 16);
}

__device__ __forceinline__ float bf2f(unsigned short s) {
    union { unsigned int u; float f; } t; t.u = (unsigned int)s << 16;
    return t.f;
}

__device__ __forceinline__ float silu_f(float v) {
    return v * __builtin_amdgcn_rcpf(1.f + __expf(-v));
}

__device__ __forceinline__ unsigned int pack_bf16(float lo, float hi) {
    union { __hip_bfloat162 h; unsigned int u; } r;
    r.h = __float22bfloat162_rn(float2{lo, hi});
    return r.u;
}

__device__ __forceinline__ void gl_lds16(const void* g, void* l) {
    __builtin_amdgcn_global_load_lds(
        (const __attribute__((address_space(1))) void*)g,
        (__attribute__((address_space(3))) void*)l, 16, 0, 0);
}

// swizzled LDS 16B-chunk read: row stride 128B, chunk index XOR (row&7)
__device__ __forceinline__ short8 rd_swz(const unsigned short* base, int row, int chunk) {
    const char* b = (const char*)base;
    return *(const short8*)(b + row * 128 + (((chunk ^ (row & 7)) << 4)));
}

// ---------------- merged prep: convert x->bf16; transpose W_in, W_out ----------------
__device__ __forceinline__ void transpose32(const float* __restrict__ in,
                                            unsigned short* __restrict__ out,
                                            int R, int C, int bx, int by, int tid) {
    __shared__ float tile[32][33];
    int tx = tid & 31, ty = tid >> 5;   // (32,8)
    int c0 = bx * 32, r0 = by * 32;
    #pragma unroll
    for (int i = 0; i < 32; i += 8)
        tile[ty + i][tx] = in[(size_t)(r0 + ty + i) * C + c0 + tx];
    __syncthreads();
    #pragma unroll
    for (int i = 0; i < 32; i += 8)
        out[(size_t)(c0 + ty + i) * R + r0 + tx] = f2bf(tile[tx][ty + i]);
}

__global__ __launch_bounds__(256) void k_prep(const float* __restrict__ x,
                                              unsigned short* __restrict__ xb,
                                              const float* __restrict__ W_in,
                                              unsigned short* __restrict__ WinT,
                                              const float* __restrict__ W_out,
                                              unsigned short* __restrict__ WoutT) {
    const int b = blockIdx.x, tid = threadIdx.x;
    if (b < 4096) {
        int i = b * 256 + tid;
        float4 v = ((const float4*)x)[i];
        union { unsigned short s[4]; uint2 u; } o;
        o.s[0] = f2bf(v.x); o.s[1] = f2bf(v.y); o.s[2] = f2bf(v.z); o.s[3] = f2bf(v.w);
        ((uint2*)xb)[i] = o.u;
    } else if (b < 8192) {
        int bb = b - 4096;             // 128 x 32
        transpose32(W_in, WinT, 1024, 4096, bb & 127, bb >> 7, tid);
    } else {
        int bb = b - 8192;             // 32 x 32
        transpose32(W_out, WoutT, 1024, 1024, bb & 31, bb >> 5, tid);
    }
}

// ---------------- GEMM1: 256x256 tile, BK=64, 8 waves, 4-phase, counted vmcnt ----------------
__device__ __forceinline__ void stage256o(const unsigned short* __restrict__ A,
                                          const unsigned short* __restrict__ Bt,
                                          int row0, int col0, int k0,
                                          unsigned short* sAbuf, unsigned short* sBbuf,
                                          int tid) {
    #pragma unroll
    for (int q = 0; q < 4; ++q) {
        int c = tid + 512 * q;
        int rr = c >> 3;
        int kcs = (c & 7) ^ (rr & 7);
        gl_lds16(Bt + (size_t)(col0 + rr) * 1024 + k0 + kcs * 8, sBbuf + c * 8);
    }
    __builtin_amdgcn_sched_barrier(0);
    #pragma unroll
    for (int p = 0; p < 4; ++p) {
        int c = (tid < 256) ? (256 * p + tid) : (1024 + 256 * p + (tid - 256));
        int rr = c >> 3;
        int kcs = (c & 7) ^ (rr & 7);
        gl_lds16(A + (size_t)(row0 + rr) * 1024 + k0 + kcs * 8, sAbuf + c * 8);
        __builtin_amdgcn_sched_barrier(0);
    }
}

__global__ __launch_bounds__(512, 2) void k_gemm1_256(
    const unsigned short* __restrict__ A, const unsigned short* __restrict__ Bt,
    const float* __restrict__ bias,
    unsigned short* __restrict__ outU, unsigned short* __restrict__ outVt,
    unsigned short* __restrict__ outQ, unsigned short* __restrict__ outK)
{
    __shared__ __align__(16) unsigned short sA[2][256 * 64];
    __shared__ __align__(16) unsigned short sB[2][256 * 64];   // 128 KiB total

    const int tid = threadIdx.x;           // 0..511
    const int lane = tid & 63, wid = tid >> 6;
    const int lr = lane & 15, lk = lane >> 4;
    const int wm = wid >> 2, wn = wid & 3; // 2M x 4N wave grid
    const int bm = blockIdx.x, bn = blockIdx.y;
    const int row0 = bm * 256, col0 = bn * 256;

    f32x4 acc[8][4] = {};

    stage256o(A, Bt, row0, col0, 0, sA[0], sB[0], tid);
    asm volatile("s_waitcnt vmcnt(0)" ::: "memory");
    __builtin_amdgcn_s_barrier();
    __builtin_amdgcn_sched_barrier(0);

    int cur = 0;
    for (int kt = 0; kt < 15; ++kt) {
        stage256o(A, Bt, row0, col0, (kt + 1) * 64, sA[cur ^ 1], sB[cur ^ 1], tid);
        short8 bf[2][4];
        #pragma unroll
        for (int kk = 0; kk < 2; ++kk)
            #pragma unroll
            for (int n = 0; n < 4; ++n)
                bf[kk][n] = rd_swz(sB[cur], wn * 64 + n * 16 + lr, kk * 4 + lk);

        #pragma unroll
        for (int ph = 0; ph < 4; ++ph) {
            short8 af[2][2];
            #pragma unroll
            for (int mm = 0; mm < 2; ++mm)
                #pragma unroll
                for (int kk = 0; kk < 2; ++kk)
                    af[mm][kk] = rd_swz(sA[cur], wm * 128 + (ph * 2 + mm) * 16 + lr, kk * 4 + lk);
            __builtin_amdgcn_s_barrier();
            __builtin_amdgcn_s_setprio(1);
            #pragma unroll
            for (int mm = 0; mm < 2; ++mm)
                #pragma unroll
                for (int n = 0; n < 4; ++n)
                    #pragma unroll
                    for (int kk = 0; kk < 2; ++kk)
                        acc[ph * 2 + mm][n] = __builtin_amdgcn_mfma_f32_16x16x32_bf16(
                            af[mm][kk], bf[kk][n], acc[ph * 2 + mm][n], 0, 0, 0);
            __builtin_amdgcn_s_setprio(0);
            // counted ladder: wait only for the chunks the NEXT phase reads
            if (ph == 0)      asm volatile("s_waitcnt vmcnt(10)" ::: "memory");
            else if (ph == 1) asm volatile("s_waitcnt vmcnt(9)" ::: "memory");
            else if (ph == 2) asm volatile("s_waitcnt vmcnt(8)" ::: "memory");
            else              asm volatile("s_waitcnt vmcnt(3)" ::: "memory");
            __builtin_amdgcn_s_barrier();
        }
        __builtin_amdgcn_sched_barrier(0);
        cur ^= 1;
    }

    // last K-tile: ladder {2,1,0}
    {
        short8 bf[2][4];
        #pragma unroll
        for (int kk = 0; kk < 2; ++kk)
            #pragma unroll
            for (int n = 0; n < 4; ++n)
                bf[kk][n] = rd_swz(sB[cur], wn * 64 + n * 16 + lr, kk * 4 + lk);
        #pragma unroll
        for (int ph = 0; ph < 4; ++ph) {
            short8 af[2][2];
            #pragma unroll
            for (int mm = 0; mm < 2; ++mm)
                #pragma unroll
                for (int kk = 0; kk < 2; ++kk)
                    af[mm][kk] = rd_swz(sA[cur], wm * 128 + (ph * 2 + mm) * 16 + lr, kk * 4 + lk);
            __builtin_amdgcn_s_barrier();
            __builtin_amdgcn_s_setprio(1);
            #pragma unroll
            for (int mm = 0; mm < 2; ++mm)
                #pragma unroll
                for (int n = 0; n < 4; ++n)
                    #pragma unroll
                    for (int kk = 0; kk < 2; ++kk)
                        acc[ph * 2 + mm][n] = __builtin_amdgcn_mfma_f32_16x16x32_bf16(
                            af[mm][kk], bf[kk][n], acc[ph * 2 + mm][n], 0, 0, 0);
            __builtin_amdgcn_s_setprio(0);
            if (ph == 0)      { asm volatile("s_waitcnt vmcnt(2)" ::: "memory"); __builtin_amdgcn_s_barrier(); }
            else if (ph == 1) { asm volatile("s_waitcnt vmcnt(1)" ::: "memory"); __builtin_amdgcn_s_barrier(); }
            else if (ph == 2) { asm volatile("s_waitcnt vmcnt(0)" ::: "memory"); __builtin_amdgcn_s_barrier(); }
        }
    }

    // epilogue: whole block lies in one section
    const int sec = bn >> 2;
    #pragma unroll
    for (int n = 0; n < 4; ++n) {
        const int cg = col0 + wn * 64 + n * 16 + lr;
        const int cc = cg & 1023;
        const float bv = bias[cg];
        #pragma unroll
        for (int m = 0; m < 8; ++m) {
            const int rg0 = row0 + wm * 128 + m * 16 + lk * 4;
            float sv[4];
            #pragma unroll
            for (int j = 0; j < 4; ++j)
                sv[j] = silu_f(acc[m][n][j] + bv);
            if (sec == 0) {
                #pragma unroll
                for (int j = 0; j < 4; ++j)
                    outU[((size_t)(rg0 + j) << 10) + cc] = f2bf(sv[j]);
            } else if (sec == 1) {
                union { unsigned short s[4]; uint2 u; } pk;
                #pragma unroll
                for (int j = 0; j < 4; ++j) pk.s[j] = f2bf(sv[j]);
                *(uint2*)(outVt + ((size_t)cc << 12) + rg0) = pk.u;
            } else if (sec == 2) {
                #pragma unroll
                for (int j = 0; j < 4; ++j)
                    outQ[((size_t)(rg0 + j) << 10) + cc] = f2bf(sv[j] * 0.125f);
            } else {
                #pragma unroll
                for (int j = 0; j < 4; ++j)
                    outK[((size_t)(rg0 + j) << 10) + cc] = f2bf(sv[j]);
            }
        }
    }
}

// ---------------- GEMM2: 128x128 tile, BK=64, 4 waves, 2-phase, counted vmcnt ----------------
__device__ __forceinline__ void stage128o(const unsigned short* __restrict__ A,
                                          const unsigned short* __restrict__ Bt,
                                          int row0, int col0, int k0,
                                          unsigned short* sAbuf, unsigned short* sBbuf,
                                          int tid) {
    #pragma unroll
    for (int q = 0; q < 4; ++q) {
        int c = tid + 256 * q;
        int rr = c >> 3;
        int kcs = (c & 7) ^ (rr & 7);
        gl_lds16(Bt + (size_t)(col0 + rr) * 1024 + k0 + kcs * 8, sBbuf + c * 8);
    }
    __builtin_amdgcn_sched_barrier(0);
    {
        int c = tid;          int rr = c >> 3; int kcs = (c & 7) ^ (rr & 7);
        gl_lds16(A + (size_t)(row0 + rr) * 1024 + k0 + kcs * 8, sAbuf + c * 8);
        c = 512 + tid;        rr = c >> 3;     kcs = (c & 7) ^ (rr & 7);
        gl_lds16(A + (size_t)(row0 + rr) * 1024 + k0 + kcs * 8, sAbuf + c * 8);
    }
    __builtin_amdgcn_sched_barrier(0);
    {
        int c = 256 + tid;    int rr = c >> 3; int kcs = (c & 7) ^ (rr & 7);
        gl_lds16(A + (size_t)(row0 + rr) * 1024 + k0 + kcs * 8, sAbuf + c * 8);
        c = 768 + tid;        rr = c >> 3;     kcs = (c & 7) ^ (rr & 7);
        gl_lds16(A + (size_t)(row0 + rr) * 1024 + k0 + kcs * 8, sAbuf + c * 8);
    }
    __builtin_amdgcn_sched_barrier(0);
}

__global__ __launch_bounds__(256, 2) void k_gemm2(
    const unsigned short* __restrict__ A, const unsigned short* __restrict__ Bt,
    const float* __restrict__ bias, float* __restrict__ outY)
{
    __shared__ __align__(16) unsigned short sA[2][128 * 64];
    __shared__ __align__(16) unsigned short sB[2][128 * 64];   // 64 KiB total

    const int tid = threadIdx.x;           // 0..255
    const int lane = tid & 63, wid = tid >> 6;
    const int lr = lane & 15, lk = lane >> 4;
    const int wm = wid >> 1, wn = wid & 1; // 2M x 2N wave grid, 64x64 per wave
    const int bm = blockIdx.x, bn = blockIdx.y;
    const int row0 = bm * 128, col0 = bn * 128;

    f32x4 acc[4][4] = {};

    stage128o(A, Bt, row0, col0, 0, sA[0], sB[0], tid);
    asm volatile("s_waitcnt vmcnt(0)" ::: "memory");
    __builtin_amdgcn_s_barrier();
    __builtin_amdgcn_sched_barrier(0);

    int cur = 0;
    for (int kt = 0; kt < 15; ++kt) {
        stage128o(A, Bt, row0, col0, (kt + 1) * 64, sA[cur ^ 1], sB[cur ^ 1], tid);
        short8 bf[2][4];
        #pragma unroll
        for (int kk = 0; kk < 2; ++kk)
            #pragma unroll
            for (int n = 0; n < 4; ++n)
                bf[kk][n] = rd_swz(sB[cur], wn * 64 + n * 16 + lr, kk * 4 + lk);

        #pragma unroll
        for (int ph = 0; ph < 2; ++ph) {
            short8 af[2][2];
            #pragma unroll
            for (int mm = 0; mm < 2; ++mm)
                #pragma unroll
                for (int kk = 0; kk < 2; ++kk)
                    af[mm][kk] = rd_swz(sA[cur], wm * 64 + (ph * 2 + mm) * 16 + lr, kk * 4 + lk);
            __builtin_amdgcn_s_barrier();
            __builtin_amdgcn_s_setprio(1);
            #pragma unroll
            for (int mm = 0; mm < 2; ++mm)
                #pragma unroll
                for (int n = 0; n < 4; ++n)
                    #pragma unroll
                    for (int kk = 0; kk < 2; ++kk)
                        acc[ph * 2 + mm][n] = __builtin_amdgcn_mfma_f32_16x16x32_bf16(
                            af[mm][kk], bf[kk][n], acc[ph * 2 + mm][n], 0, 0, 0);
            __builtin_amdgcn_s_setprio(0);
            if (ph == 0) asm volatile("s_waitcnt vmcnt(10)" ::: "memory");
            else         asm volatile("s_waitcnt vmcnt(2)" ::: "memory");
            __builtin_amdgcn_s_barrier();
        }
        __builtin_amdgcn_sched_barrier(0);
        cur ^= 1;
    }

    // last K-tile
    {
        short8 bf[2][4];
        #pragma unroll
        for (int kk = 0; kk < 2; ++kk)
            #pragma unroll
            for (int n = 0; n < 4; ++n)
                bf[kk][n] = rd_swz(sB[cur], wn * 64 + n * 16 + lr, kk * 4 + lk);
        #pragma unroll
        for (int ph = 0; ph < 2; ++ph) {
            short8 af[2][2];
            #pragma unroll
            for (int mm = 0; mm < 2; ++mm)
                #pragma unroll
                for (int kk = 0; kk < 2; ++kk)
                    af[mm][kk] = rd_swz(sA[cur], wm * 64 + (ph * 2 + mm) * 16 + lr, kk * 4 + lk);
            __builtin_amdgcn_s_barrier();
            __builtin_amdgcn_s_setprio(1);
            #pragma unroll
            for (int mm = 0; mm < 2; ++mm)
                #pragma unroll
                for (int n = 0; n < 4; ++n)
                    #pragma unroll
                    for (int kk = 0; kk < 2; ++kk)
                        acc[ph * 2 + mm][n] = __builtin_amdgcn_mfma_f32_16x16x32_bf16(
                            af[mm][kk], bf[kk][n], acc[ph * 2 + mm][n], 0, 0, 0);
            __builtin_amdgcn_s_setprio(0);
            if (ph == 0) { asm volatile("s_waitcnt vmcnt(0)" ::: "memory"); __builtin_amdgcn_s_barrier(); }
        }
    }

    #pragma unroll
    for (int n = 0; n < 4; ++n) {
        const int cg = col0 + wn * 64 + n * 16 + lr;
        const float bv = bias[cg];
        #pragma unroll
        for (int m = 0; m < 4; ++m) {
            const int rg0 = row0 + wm * 64 + m * 16 + lk * 4;
            #pragma unroll
            for (int j = 0; j < 4; ++j)
                outY[(size_t)(rg0 + j) * 1024 + cg] = acc[m][n][j] + bv;
        }
    }
}

// ---------------- fused pointwise attention ----------------
// grid: 1024 blocks x 256 threads; QBLK=64 (4 waves x 16 rows), KVBLK=64.
// 32 KB LDS (sK dbuf + sVt SINGLE + sP) -> 5 blocks/CU, 20 waves/CU.
// V staged at iteration top, drained with counted vmcnt(6) just before PV
// (QK+P phase ~500cy of cover; K/V are L2-resident under the XCD decode).
// SWAPPED QK^T (S[k][q]); rab via float4; P via cvt_pk + ds_write_b64.
// AV is UNSCALED (no 1/(q+1)); k_ln compensates exactly via eps scaling.
__global__ __launch_bounds__(256, 5) void k_attn(
    const unsigned short* __restrict__ Qb,
    const unsigned short* __restrict__ Kb,
    const unsigned short* __restrict__ Vt,   // [1024][4096] = V transposed
    const float* __restrict__ rab,
    unsigned short* __restrict__ AV)
{
    __shared__ __align__(16) unsigned short sK[2][64 * 64];   // 16 KB
    __shared__ __align__(16) unsigned short sVt[64 * 64];     // 8 KB (single)
    __shared__ __align__(16) unsigned short sP[64 * 64];      // 8 KB -> 32 KB total

    const int tid = threadIdx.x;
    const int lane = tid & 63;
    const int w = tid >> 6;        // 0..3
    const int lr = lane & 15;
    const int lk = lane >> 4;

    const int bid = blockIdx.x;            // [0,1024)
    const int xcd = bid & 7;
    const int j_ = bid >> 3;
    const int cc_ = j_ & 31;
    const int b4 = j_ >> 5;                // 0..3
    const int h = ((b4 & 1) << 3) | xcd;
    const int bb = b4 >> 1;
    const int cc2 = (b4 >= 2) ? ((cc_ + 16) & 31) : cc_;
    const int qt = (b4 & 1) ? (31 - cc2) : cc2;
    const int q0 = qt * 64;

    // Q fragments in registers (B-operand of swapped QK; rows q0 + w*16 + lr)
    short8 qreg[2];
    #pragma unroll
    for (int ks = 0; ks < 2; ++ks)
        qreg[ks] = *(const short8*)(Qb + (((size_t)(bb * TSEQ + q0 + w * 16 + lr)) << 10)
                                     + h * 64 + ks * 32 + lk * 8);
    __builtin_amdgcn_sched_barrier(0);

    const int qloc = w * 16 + lr;        // local q row (QK output col / sP row)
    const int qcol = q0 + qloc;          // global q for this lane's S column
    const float* rabq = rab + ((size_t)h * TSEQ + qcol) * TSEQ + lk * 4;

    f32x4 acc[4] = {};

    #define STAGE_K(buf, kt_) do {                                                    \
        int k0s = (kt_) * 64;                                                         \
        for (int c = tid; c < 512; c += 256) {                                        \
            int rr = c >> 3, kc = c & 7;                                              \
            int kcs = kc ^ (rr & 7);                                                  \
            gl_lds16(Kb + (((size_t)(bb * TSEQ + k0s + rr)) << 10) + h * 64 + kcs * 8,\
                     sK[buf] + c * 8);                                                \
        }                                                                             \
    } while (0)

    #define STAGE_V(kt_) do {                                                         \
        int k0s = (kt_) * 64;                                                         \
        for (int c = tid; c < 512; c += 256) {                                        \
            int rr = c >> 3, kc = c & 7;                                              \
            int kcs = kc ^ (rr & 7);                                                  \
            gl_lds16(Vt + (((size_t)(h * 64 + rr)) << 12) + bb * TSEQ + k0s + kcs * 8,\
                     sVt + c * 8);                                                    \
        }                                                                             \
    } while (0)

    float4 rv0[4], rv1[4];

    STAGE_K(0, 0);
    __builtin_amdgcn_sched_barrier(0);
    #pragma unroll
    for (int nt = 0; nt < 4; ++nt)
        rv0[nt] = *(const float4*)(rabq + nt * 16);
    __builtin_amdgcn_sched_barrier(0);
    // drain qreg (2) + K0 stage (2); keep the 4 rab loads flying
    asm volatile("s_waitcnt vmcnt(4)" ::: "memory");
    __builtin_amdgcn_s_barrier();

    // One iteration body. RVC = this iter's rab (in regs); RVN = next iter's (loaded here).
    // V for THIS iteration staged first (oldest -> drained by vmcnt(6) pre-PV).
    #define BODY(KT, BUFC, RVC, RVN) do {                                             \
        const int k0 = (KT) * 64;                                                     \
        const bool have_next = (KT) < qt;                                             \
        STAGE_V(KT);                                                                  \
        __builtin_amdgcn_sched_barrier(0);                                            \
        if (have_next) STAGE_K((BUFC) ^ 1, (KT) + 1);                                 \
        __builtin_amdgcn_sched_barrier(0);                                            \
        if (have_next) {                                                              \
            _Pragma("unroll")                                                         \
            for (int nt = 0; nt < 4; ++nt)                                            \
                RVN[nt] = *(const float4*)(rabq + k0 + 64 + nt * 16);                 \
        }                                                                             \
        __builtin_amdgcn_sched_barrier(0);                                            \
        f32x4 s[4];                                                                   \
        _Pragma("unroll")                                                             \
        for (int nt = 0; nt < 4; ++nt) {                                              \
            s[nt][0] = RVC[nt].x; s[nt][1] = RVC[nt].y;                               \
            s[nt][2] = RVC[nt].z; s[nt][3] = RVC[nt].w;                               \
        }                                                                             \
        __builtin_amdgcn_s_setprio(1);                                                \
        _Pragma("unroll")                                                             \
        for (int ks = 0; ks < 2; ++ks) {                                              \
            _Pragma("unroll")                                                         \
            for (int nt = 0; nt < 4; ++nt)                                            \
                s[nt] = __builtin_amdgcn_mfma_f32_16x16x32_bf16(                      \
                    rd_swz(sK[BUFC], nt * 16 + lr, ks * 4 + lk), qreg[ks], s[nt], 0, 0, 0); \
        }                                                                             \
        __builtin_amdgcn_s_setprio(0);                                                \
        char* pb = (char*)sP;                                                         \
        char* paddr = pb + qloc * 128 + ((lk & 1) * 8);                               \
        if (have_next) {                                                              \
            _Pragma("unroll")                                                         \
            for (int nt = 0; nt < 4; ++nt) {                                          \
                unsigned int p01 = pack_bf16(silu_f(s[nt][0]), silu_f(s[nt][1]));     \
                unsigned int p23 = pack_bf16(silu_f(s[nt][2]), silu_f(s[nt][3]));     \
                const int chunk = nt * 2 + (lk >> 1);                                 \
                *(uint2*)(paddr + ((chunk ^ (qloc & 7)) << 4)) = make_uint2(p01, p23);\
            }                                                                         \
        } else {                                                                      \
            _Pragma("unroll")                                                         \
            for (int nt = 0; nt < 4; ++nt) {                                          \
                const int kb = k0 + nt * 16 + lk * 4;                                 \
                float a0 = (kb + 0 <= qcol) ? silu_f(s[nt][0]) : 0.f;                 \
                float a1 = (kb + 1 <= qcol) ? silu_f(s[nt][1]) : 0.f;                 \
                float a2 = (kb + 2 <= qcol) ? silu_f(s[nt][2]) : 0.f;                 \
                float a3 = (kb + 3 <= qcol) ? silu_f(s[nt][3]) : 0.f;                 \
                unsigned int p01 = pack_bf16(a0, a1);                                 \
                unsigned int p23 = pack_bf16(a2, a3);                                 \
                const int chunk = nt * 2 + (lk >> 1);                                 \
                *(uint2*)(paddr + ((chunk ^ (qloc & 7)) << 4)) = make_uint2(p01, p23);\
            }                                                                         \
        }                                                                             \
        /* V ready: outstanding = V(2)+K(2)+rab(4) -> drain V only */                 \
        if (have_next) asm volatile("s_waitcnt vmcnt(6)" ::: "memory");               \
        else           asm volatile("s_waitcnt vmcnt(0)" ::: "memory");               \
        __builtin_amdgcn_s_barrier();                                                 \
        __builtin_amdgcn_s_setprio(1);                                                \
        _Pragma("unroll")                                                             \
        for (int ks = 0; ks < 2; ++ks) {                                              \
            short8 ap = rd_swz(sP, qloc, ks * 4 + lk);                                \
            _Pragma("unroll")                                                         \
            for (int dt = 0; dt < 4; ++dt)                                            \
                acc[dt] = __builtin_amdgcn_mfma_f32_16x16x32_bf16(                    \
                    ap, rd_swz(sVt, dt * 16 + lr, ks * 4 + lk), acc[dt], 0, 0, 0);    \
        }                                                                             \
        __builtin_amdgcn_s_setprio(0);                                                \
        if (have_next) {                                                              \
            /* K-next ready; rab(4) keeps flying into next iteration */               \
            asm volatile("s_waitcnt vmcnt(4)" ::: "memory");                          \
            __builtin_amdgcn_s_barrier();                                             \
        }                                                                             \
    } while (0)

    for (int kt = 0; kt <= qt; kt += 2) {
        BODY(kt, 0, rv0, rv1);
        if (kt + 1 <= qt) BODY(kt + 1, 1, rv1, rv0);
    }
    #undef BODY
    #undef STAGE_K
    #undef STAGE_V

    #pragma unroll
    for (int dt = 0; dt < 4; ++dt)
        #pragma unroll
        for (int j = 0; j < 4; ++j)
            AV[(((size_t)(bb * TSEQ + q0 + w * 16 + lk * 4 + j)) << 10)
               + h * 64 + dt * 16 + lr] = f2bf(acc[dt][j]);
}

// ---------------- LayerNorm(AV) * U -> z (bf16) ----------------
// AV rows are scaled by c=(q+1) vs reference; LN(c*x) with eps*c^2 == LN(x) exactly.
__global__ __launch_bounds__(256) void k_ln(const unsigned short* __restrict__ AV,
                                            const unsigned short* __restrict__ U,
                                            const float* __restrict__ lnw,
                                            const float* __restrict__ lnb,
                                            unsigned short* __restrict__ z) {
    __shared__ float red[8];
    const int row = blockIdx.x, tid = threadIdx.x;
    const float c = (float)((row & (TSEQ - 1)) + 1);
    const float eps = 1e-5f * c * c;
    union { unsigned short s[4]; uint2 u; } a;
    a.u = ((const uint2*)(AV + ((size_t)row << 10)))[tid];
    float v[4];
    #pragma unroll
    for (int i = 0; i < 4; ++i) v[i] = bf2f(a.s[i]);
    float s = v[0] + v[1] + v[2] + v[3];
    float s2 = v[0] * v[0] + v[1] * v[1] + v[2] * v[2] + v[3] * v[3];
    #pragma unroll
    for (int o = 32; o > 0; o >>= 1) { s += __shfl_xor(s, o); s2 += __shfl_xor(s2, o); }
    const int w = tid >> 6;
    if ((tid & 63) == 0) { red[w] = s; red[4 + w] = s2; }
    __syncthreads();
    s = red[0] + red[1] + red[2] + red[3];
    s2 = red[4] + red[5] + red[6] + red[7];
    const float mu = s * (1.f / 1024.f);
    const float var = s2 * (1.f / 1024.f) - mu * mu;
    const float rstd = rsqrtf(var + eps);
    union { unsigned short s[4]; uint2 u; } uu;
    uu.u = ((const uint2*)(U + ((size_t)row << 10)))[tid];
    float4 lw = ((const float4*)lnw)[tid];
    float4 lb = ((const float4*)lnb)[tid];
    union { unsigned short o[4]; uint2 u; } ov;
    ov.o[0] = f2bf(((v[0] - mu) * rstd * lw.x + lb.x) * bf2f(uu.s[0]));
    ov.o[1] = f2bf(((v[1] - mu) * rstd * lw.y + lb.y) * bf2f(uu.s[1]));
    ov.o[2] = f2bf(((v[2] - mu) * rstd * lw.z + lb.z) * bf2f(uu.s[2]));
    ov.o[3] = f2bf(((v[3] - mu) * rstd * lw.w + lb.w) * bf2f(uu.s[3]));
    ((uint2*)z)[((size_t)row << 8) + tid] = ov.u;
}

extern "C" void kernel_launch(void* const* d_in, const int* in_sizes, int n_in,
                              void* d_out, int out_size, void* d_ws, size_t ws_size,
                              hipStream_t stream) {
    const float* x     = (const float*)d_in[0];
    const float* rab   = (const float*)d_in[2];
    const float* W_in  = (const float*)d_in[3];
    const float* b_in  = (const float*)d_in[4];
    const float* W_out = (const float*)d_in[5];
    const float* b_out = (const float*)d_in[6];
    const float* ln_w  = (const float*)d_in[7];
    const float* ln_b  = (const float*)d_in[8];
    float* y = (float*)d_out;

    char* ws = (char*)d_ws;
    size_t off = 0;
    auto alloc = [&](size_t bytes) -> void* {
        void* p = ws + off;
        off += (bytes + 255) & ~(size_t)255;
        return p;
    };
    unsigned short* WinT  = (unsigned short*)alloc((size_t)4096 * 1024 * 2);
    unsigned short* WoutT = (unsigned short*)alloc((size_t)1024 * 1024 * 2);
    unsigned short* xb    = (unsigned short*)alloc((size_t)MROWS * DIM * 2);
    unsigned short* Ubuf  = (unsigned short*)alloc((size_t)MROWS * DIM * 2);
    unsigned short* Qb    = (unsigned short*)alloc((size_t)MROWS * DIM * 2);
    unsigned short* Kb    = (unsigned short*)alloc((size_t)MROWS * DIM * 2);
    unsigned short* Vtb   = (unsigned short*)alloc((size_t)DIM * MROWS * 2);
    unsigned short* AV    = (unsigned short*)alloc((size_t)MROWS * DIM * 2);
    unsigned short* z     = (unsigned short*)alloc((size_t)MROWS * DIM * 2);

    // merged prep: x->bf16 + both weight transposes
    k_prep<<<dim3(9216), dim3(256), 0, stream>>>(x, xb, W_in, WinT, W_out, WoutT);
    // GEMM1 (256^2 4-phase, counted vmcnt): h = silu(x @ W_in + b_in) -> U, V^T, Q(*alpha), K
    k_gemm1_256<<<dim3(16, 16), dim3(512), 0, stream>>>(xb, WinT, b_in, Ubuf, Vtb, Qb, Kb);
    // attention (32 KB LDS, 5 blocks/CU; AV unscaled, bf16)
    k_attn<<<dim3(1024), dim3(256), 0, stream>>>(Qb, Kb, Vtb, rab, AV);
    // LN * U (eps compensated per-row)
    k_ln<<<dim3(MROWS), dim3(256), 0, stream>>>(AV, Ubuf, ln_w, ln_b, z);
    // GEMM2 (128^2 BK=64 2-phase, counted vmcnt): y = z @ W_out + b_out
    k_gemm2<<<dim3(32, 8), dim3(256), 0, stream>>>(z, WoutT, b_out, y);
}

// Round 14
// 169.496 us; speedup vs baseline: 1.2960x; 1.2960x over previous
//
#include <hip/hip_runtime.h>
#include <hip/hip_bf16.h>

// Problem constants
#define BATCH 2
#define TSEQ 2048
#define DIM 1024
#define NH 16
#define HDIM 64
#define MROWS (BATCH * TSEQ)   // 4096

typedef __attribute__((ext_vector_type(4))) float f32x4;
typedef __attribute__((ext_vector_type(8))) short short8;

__device__ __forceinline__ unsigned short f2bf(float f) {
    union { float f; unsigned int u; } x; x.f = f;
    unsigned int r = x.u + 0x7fffu + ((x.u >> 16) & 1u);
    return (unsigned short)(r >> 16);
}

__device__ __forceinline__ float bf2f(unsigned short s) {
    union { unsigned int u; float f; } t; t.u = (unsigned int)s << 16;
    return t.f;
}

__device__ __forceinline__ float silu_f(float v) {
    return v * __builtin_amdgcn_rcpf(1.f + __expf(-v));
}

__device__ __forceinline__ unsigned int pack_bf16(float lo, float hi) {
    union { __hip_bfloat162 h; unsigned int u; } r;
    r.h = __float22bfloat162_rn(float2{lo, hi});
    return r.u;
}

__device__ __forceinline__ void gl_lds16(const void* g, void* l) {
    __builtin_amdgcn_global_load_lds(
        (const __attribute__((address_space(1))) void*)g,
        (__attribute__((address_space(3))) void*)l, 16, 0, 0);
}

// swizzled LDS 16B-chunk read: row stride 128B, chunk index XOR (row&7)
__device__ __forceinline__ short8 rd_swz(const unsigned short* base, int row, int chunk) {
    const char* b = (const char*)base;
    return *(const short8*)(b + row * 128 + (((chunk ^ (row & 7)) << 4)));
}

// ---------------- merged prep: convert x->bf16; transpose W_in, W_out ----------------
__device__ __forceinline__ void transpose32(const float* __restrict__ in,
                                            unsigned short* __restrict__ out,
                                            int R, int C, int bx, int by, int tid) {
    __shared__ float tile[32][33];
    int tx = tid & 31, ty = tid >> 5;   // (32,8)
    int c0 = bx * 32, r0 = by * 32;
    #pragma unroll
    for (int i = 0; i < 32; i += 8)
        tile[ty + i][tx] = in[(size_t)(r0 + ty + i) * C + c0 + tx];
    __syncthreads();
    #pragma unroll
    for (int i = 0; i < 32; i += 8)
        out[(size_t)(c0 + ty + i) * R + r0 + tx] = f2bf(tile[tx][ty + i]);
}

__global__ __launch_bounds__(256) void k_prep(const float* __restrict__ x,
                                              unsigned short* __restrict__ xb,
                                              const float* __restrict__ W_in,
                                              unsigned short* __restrict__ WinT,
                                              const float* __restrict__ W_out,
                                              unsigned short* __restrict__ WoutT) {
    const int b = blockIdx.x, tid = threadIdx.x;
    if (b < 4096) {
        int i = b * 256 + tid;
        float4 v = ((const float4*)x)[i];
        union { unsigned short s[4]; uint2 u; } o;
        o.s[0] = f2bf(v.x); o.s[1] = f2bf(v.y); o.s[2] = f2bf(v.z); o.s[3] = f2bf(v.w);
        ((uint2*)xb)[i] = o.u;
    } else if (b < 8192) {
        int bb = b - 4096;             // 128 x 32
        transpose32(W_in, WinT, 1024, 4096, bb & 127, bb >> 7, tid);
    } else {
        int bb = b - 8192;             // 32 x 32
        transpose32(W_out, WoutT, 1024, 1024, bb & 31, bb >> 5, tid);
    }
}

// ---------------- GEMM1: 256x256 tile, BK=64, 8 waves, 4-phase, counted vmcnt ----------------
__device__ __forceinline__ void stage256o(const unsigned short* __restrict__ A,
                                          const unsigned short* __restrict__ Bt,
                                          int row0, int col0, int k0,
                                          unsigned short* sAbuf, unsigned short* sBbuf,
                                          int tid) {
    #pragma unroll
    for (int q = 0; q < 4; ++q) {
        int c = tid + 512 * q;
        int rr = c >> 3;
        int kcs = (c & 7) ^ (rr & 7);
        gl_lds16(Bt + (size_t)(col0 + rr) * 1024 + k0 + kcs * 8, sBbuf + c * 8);
    }
    __builtin_amdgcn_sched_barrier(0);
    #pragma unroll
    for (int p = 0; p < 4; ++p) {
        int c = (tid < 256) ? (256 * p + tid) : (1024 + 256 * p + (tid - 256));
        int rr = c >> 3;
        int kcs = (c & 7) ^ (rr & 7);
        gl_lds16(A + (size_t)(row0 + rr) * 1024 + k0 + kcs * 8, sAbuf + c * 8);
        __builtin_amdgcn_sched_barrier(0);
    }
}

__global__ __launch_bounds__(512, 2) void k_gemm1_256(
    const unsigned short* __restrict__ A, const unsigned short* __restrict__ Bt,
    const float* __restrict__ bias,
    unsigned short* __restrict__ outU, unsigned short* __restrict__ outVt,
    unsigned short* __restrict__ outQ, unsigned short* __restrict__ outK)
{
    __shared__ __align__(16) unsigned short sA[2][256 * 64];
    __shared__ __align__(16) unsigned short sB[2][256 * 64];   // 128 KiB total

    const int tid = threadIdx.x;           // 0..511
    const int lane = tid & 63, wid = tid >> 6;
    const int lr = lane & 15, lk = lane >> 4;
    const int wm = wid >> 2, wn = wid & 3; // 2M x 4N wave grid
    const int bm = blockIdx.x, bn = blockIdx.y;
    const int row0 = bm * 256, col0 = bn * 256;

    f32x4 acc[8][4] = {};

    stage256o(A, Bt, row0, col0, 0, sA[0], sB[0], tid);
    asm volatile("s_waitcnt vmcnt(0)" ::: "memory");
    __builtin_amdgcn_s_barrier();
    __builtin_amdgcn_sched_barrier(0);

    int cur = 0;
    for (int kt = 0; kt < 15; ++kt) {
        stage256o(A, Bt, row0, col0, (kt + 1) * 64, sA[cur ^ 1], sB[cur ^ 1], tid);
        short8 bf[2][4];
        #pragma unroll
        for (int kk = 0; kk < 2; ++kk)
            #pragma unroll
            for (int n = 0; n < 4; ++n)
                bf[kk][n] = rd_swz(sB[cur], wn * 64 + n * 16 + lr, kk * 4 + lk);

        #pragma unroll
        for (int ph = 0; ph < 4; ++ph) {
            short8 af[2][2];
            #pragma unroll
            for (int mm = 0; mm < 2; ++mm)
                #pragma unroll
                for (int kk = 0; kk < 2; ++kk)
                    af[mm][kk] = rd_swz(sA[cur], wm * 128 + (ph * 2 + mm) * 16 + lr, kk * 4 + lk);
            __builtin_amdgcn_s_barrier();
            __builtin_amdgcn_s_setprio(1);
            #pragma unroll
            for (int mm = 0; mm < 2; ++mm)
                #pragma unroll
                for (int n = 0; n < 4; ++n)
                    #pragma unroll
                    for (int kk = 0; kk < 2; ++kk)
                        acc[ph * 2 + mm][n] = __builtin_amdgcn_mfma_f32_16x16x32_bf16(
                            af[mm][kk], bf[kk][n], acc[ph * 2 + mm][n], 0, 0, 0);
            __builtin_amdgcn_s_setprio(0);
            // counted ladder: wait only for the chunks the NEXT phase reads
            if (ph == 0)      asm volatile("s_waitcnt vmcnt(10)" ::: "memory");
            else if (ph == 1) asm volatile("s_waitcnt vmcnt(9)" ::: "memory");
            else if (ph == 2) asm volatile("s_waitcnt vmcnt(8)" ::: "memory");
            else              asm volatile("s_waitcnt vmcnt(3)" ::: "memory");
            __builtin_amdgcn_s_barrier();
        }
        __builtin_amdgcn_sched_barrier(0);
        cur ^= 1;
    }

    // last K-tile: ladder {2,1,0}
    {
        short8 bf[2][4];
        #pragma unroll
        for (int kk = 0; kk < 2; ++kk)
            #pragma unroll
            for (int n = 0; n < 4; ++n)
                bf[kk][n] = rd_swz(sB[cur], wn * 64 + n * 16 + lr, kk * 4 + lk);
        #pragma unroll
        for (int ph = 0; ph < 4; ++ph) {
            short8 af[2][2];
            #pragma unroll
            for (int mm = 0; mm < 2; ++mm)
                #pragma unroll
                for (int kk = 0; kk < 2; ++kk)
                    af[mm][kk] = rd_swz(sA[cur], wm * 128 + (ph * 2 + mm) * 16 + lr, kk * 4 + lk);
            __builtin_amdgcn_s_barrier();
            __builtin_amdgcn_s_setprio(1);
            #pragma unroll
            for (int mm = 0; mm < 2; ++mm)
                #pragma unroll
                for (int n = 0; n < 4; ++n)
                    #pragma unroll
                    for (int kk = 0; kk < 2; ++kk)
                        acc[ph * 2 + mm][n] = __builtin_amdgcn_mfma_f32_16x16x32_bf16(
                            af[mm][kk], bf[kk][n], acc[ph * 2 + mm][n], 0, 0, 0);
            __builtin_amdgcn_s_setprio(0);
            if (ph == 0)      { asm volatile("s_waitcnt vmcnt(2)" ::: "memory"); __builtin_amdgcn_s_barrier(); }
            else if (ph == 1) { asm volatile("s_waitcnt vmcnt(1)" ::: "memory"); __builtin_amdgcn_s_barrier(); }
            else if (ph == 2) { asm volatile("s_waitcnt vmcnt(0)" ::: "memory"); __builtin_amdgcn_s_barrier(); }
        }
    }

    // epilogue: whole block lies in one section
    const int sec = bn >> 2;
    #pragma unroll
    for (int n = 0; n < 4; ++n) {
        const int cg = col0 + wn * 64 + n * 16 + lr;
        const int cc = cg & 1023;
        const float bv = bias[cg];
        #pragma unroll
        for (int m = 0; m < 8; ++m) {
            const int rg0 = row0 + wm * 128 + m * 16 + lk * 4;
            float sv[4];
            #pragma unroll
            for (int j = 0; j < 4; ++j)
                sv[j] = silu_f(acc[m][n][j] + bv);
            if (sec == 0) {
                #pragma unroll
                for (int j = 0; j < 4; ++j)
                    outU[((size_t)(rg0 + j) << 10) + cc] = f2bf(sv[j]);
            } else if (sec == 1) {
                union { unsigned short s[4]; uint2 u; } pk;
                #pragma unroll
                for (int j = 0; j < 4; ++j) pk.s[j] = f2bf(sv[j]);
                *(uint2*)(outVt + ((size_t)cc << 12) + rg0) = pk.u;
            } else if (sec == 2) {
                #pragma unroll
                for (int j = 0; j < 4; ++j)
                    outQ[((size_t)(rg0 + j) << 10) + cc] = f2bf(sv[j] * 0.125f);
            } else {
                #pragma unroll
                for (int j = 0; j < 4; ++j)
                    outK[((size_t)(rg0 + j) << 10) + cc] = f2bf(sv[j]);
            }
        }
    }
}

// ---------------- GEMM2: 128x128 tile, BK=64, 4 waves, 2-phase, counted vmcnt ----------------
__device__ __forceinline__ void stage128o(const unsigned short* __restrict__ A,
                                          const unsigned short* __restrict__ Bt,
                                          int row0, int col0, int k0,
                                          unsigned short* sAbuf, unsigned short* sBbuf,
                                          int tid) {
    #pragma unroll
    for (int q = 0; q < 4; ++q) {
        int c = tid + 256 * q;
        int rr = c >> 3;
        int kcs = (c & 7) ^ (rr & 7);
        gl_lds16(Bt + (size_t)(col0 + rr) * 1024 + k0 + kcs * 8, sBbuf + c * 8);
    }
    __builtin_amdgcn_sched_barrier(0);
    {
        int c = tid;          int rr = c >> 3; int kcs = (c & 7) ^ (rr & 7);
        gl_lds16(A + (size_t)(row0 + rr) * 1024 + k0 + kcs * 8, sAbuf + c * 8);
        c = 512 + tid;        rr = c >> 3;     kcs = (c & 7) ^ (rr & 7);
        gl_lds16(A + (size_t)(row0 + rr) * 1024 + k0 + kcs * 8, sAbuf + c * 8);
    }
    __builtin_amdgcn_sched_barrier(0);
    {
        int c = 256 + tid;    int rr = c >> 3; int kcs = (c & 7) ^ (rr & 7);
        gl_lds16(A + (size_t)(row0 + rr) * 1024 + k0 + kcs * 8, sAbuf + c * 8);
        c = 768 + tid;        rr = c >> 3;     kcs = (c & 7) ^ (rr & 7);
        gl_lds16(A + (size_t)(row0 + rr) * 1024 + k0 + kcs * 8, sAbuf + c * 8);
    }
    __builtin_amdgcn_sched_barrier(0);
}

__global__ __launch_bounds__(256, 2) void k_gemm2(
    const unsigned short* __restrict__ A, const unsigned short* __restrict__ Bt,
    const float* __restrict__ bias, float* __restrict__ outY)
{
    __shared__ __align__(16) unsigned short sA[2][128 * 64];
    __shared__ __align__(16) unsigned short sB[2][128 * 64];   // 64 KiB total

    const int tid = threadIdx.x;           // 0..255
    const int lane = tid & 63, wid = tid >> 6;
    const int lr = lane & 15, lk = lane >> 4;
    const int wm = wid >> 1, wn = wid & 1; // 2M x 2N wave grid, 64x64 per wave
    const int bm = blockIdx.x, bn = blockIdx.y;
    const int row0 = bm * 128, col0 = bn * 128;

    f32x4 acc[4][4] = {};

    stage128o(A, Bt, row0, col0, 0, sA[0], sB[0], tid);
    asm volatile("s_waitcnt vmcnt(0)" ::: "memory");
    __builtin_amdgcn_s_barrier();
    __builtin_amdgcn_sched_barrier(0);

    int cur = 0;
    for (int kt = 0; kt < 15; ++kt) {
        stage128o(A, Bt, row0, col0, (kt + 1) * 64, sA[cur ^ 1], sB[cur ^ 1], tid);
        short8 bf[2][4];
        #pragma unroll
        for (int kk = 0; kk < 2; ++kk)
            #pragma unroll
            for (int n = 0; n < 4; ++n)
                bf[kk][n] = rd_swz(sB[cur], wn * 64 + n * 16 + lr, kk * 4 + lk);

        #pragma unroll
        for (int ph = 0; ph < 2; ++ph) {
            short8 af[2][2];
            #pragma unroll
            for (int mm = 0; mm < 2; ++mm)
                #pragma unroll
                for (int kk = 0; kk < 2; ++kk)
                    af[mm][kk] = rd_swz(sA[cur], wm * 64 + (ph * 2 + mm) * 16 + lr, kk * 4 + lk);
            __builtin_amdgcn_s_barrier();
            __builtin_amdgcn_s_setprio(1);
            #pragma unroll
            for (int mm = 0; mm < 2; ++mm)
                #pragma unroll
                for (int n = 0; n < 4; ++n)
                    #pragma unroll
                    for (int kk = 0; kk < 2; ++kk)
                        acc[ph * 2 + mm][n] = __builtin_amdgcn_mfma_f32_16x16x32_bf16(
                            af[mm][kk], bf[kk][n], acc[ph * 2 + mm][n], 0, 0, 0);
            __builtin_amdgcn_s_setprio(0);
            if (ph == 0) asm volatile("s_waitcnt vmcnt(10)" ::: "memory");
            else         asm volatile("s_waitcnt vmcnt(2)" ::: "memory");
            __builtin_amdgcn_s_barrier();
        }
        __builtin_amdgcn_sched_barrier(0);
        cur ^= 1;
    }

    // last K-tile
    {
        short8 bf[2][4];
        #pragma unroll
        for (int kk = 0; kk < 2; ++kk)
            #pragma unroll
            for (int n = 0; n < 4; ++n)
                bf[kk][n] = rd_swz(sB[cur], wn * 64 + n * 16 + lr, kk * 4 + lk);
        #pragma unroll
        for (int ph = 0; ph < 2; ++ph) {
            short8 af[2][2];
            #pragma unroll
            for (int mm = 0; mm < 2; ++mm)
                #pragma unroll
                for (int kk = 0; kk < 2; ++kk)
                    af[mm][kk] = rd_swz(sA[cur], wm * 64 + (ph * 2 + mm) * 16 + lr, kk * 4 + lk);
            __builtin_amdgcn_s_barrier();
            __builtin_amdgcn_s_setprio(1);
            #pragma unroll
            for (int mm = 0; mm < 2; ++mm)
                #pragma unroll
                for (int n = 0; n < 4; ++n)
                    #pragma unroll
                    for (int kk = 0; kk < 2; ++kk)
                        acc[ph * 2 + mm][n] = __builtin_amdgcn_mfma_f32_16x16x32_bf16(
                            af[mm][kk], bf[kk][n], acc[ph * 2 + mm][n], 0, 0, 0);
            __builtin_amdgcn_s_setprio(0);
            if (ph == 0) { asm volatile("s_waitcnt vmcnt(0)" ::: "memory"); __builtin_amdgcn_s_barrier(); }
        }
    }

    #pragma unroll
    for (int n = 0; n < 4; ++n) {
        const int cg = col0 + wn * 64 + n * 16 + lr;
        const float bv = bias[cg];
        #pragma unroll
        for (int m = 0; m < 4; ++m) {
            const int rg0 = row0 + wm * 64 + m * 16 + lk * 4;
            #pragma unroll
            for (int j = 0; j < 4; ++j)
                outY[(size_t)(rg0 + j) * 1024 + cg] = acc[m][n][j] + bv;
        }
    }
}

// ---------------- fused pointwise attention (paired batches, 8 waves) ----------------
// grid: 512 blocks x 512 threads; QBLK=64, KVBLK=64.
// Waves 0-3 -> batch 0, waves 4-7 -> batch 1 (same q-range). One block stages
// K/V for both batches (1 chunk/thread/tile); rab loads of the bb=1 waves hit
// L1 (same addresses as bb=0 waves) -> rab L3 traffic halves vs split-batch.
// LDS 80 KB -> 2 blocks/CU = 16 waves/CU (same as round 12).
// Decode: xcd=bid&7 == h&7 (L2 locality); blocks bid and bid+256 share a CU
// with qt = r and 31-r -> 33 iters/CU (balanced).
// SWAPPED QK^T (S[k][q]); rab via float4; P via cvt_pk + ds_write_b64.
// AV is UNSCALED (no 1/(q+1)); k_ln compensates exactly via eps scaling.
__global__ __launch_bounds__(512, 4) void k_attn(
    const unsigned short* __restrict__ Qb,
    const unsigned short* __restrict__ Kb,
    const unsigned short* __restrict__ Vt,   // [1024][4096] = V transposed
    const float* __restrict__ rab,
    unsigned short* __restrict__ AV)
{
    __shared__ __align__(16) unsigned short sK[2][2][64 * 64];   // [buf][bb] 32 KB
    __shared__ __align__(16) unsigned short sVt[2][2][64 * 64];  // 32 KB
    __shared__ __align__(16) unsigned short sP[2][64 * 64];      // 16 KB -> 80 KB

    const int tid = threadIdx.x;          // 0..511
    const int lane = tid & 63;
    const int w = tid >> 6;               // 0..7
    const int bw = w >> 2;                // batch of this wave
    const int wq = w & 3;                 // q-strip
    const int lr = lane & 15;
    const int lk = lane >> 4;

    const int bid = blockIdx.x;           // [0,512)
    const int xcd = bid & 7;
    const int h = (((bid >> 3) & 1) << 3) | xcd;
    const int r_ = (bid >> 4) & 15;
    const int half = bid >> 8;
    const int qt = half ? (31 - r_) : r_;
    const int q0 = qt * 64;

    // Q fragments in registers (B-operand of swapped QK; rows q0 + wq*16 + lr)
    short8 qreg[2];
    #pragma unroll
    for (int ks = 0; ks < 2; ++ks)
        qreg[ks] = *(const short8*)(Qb + (((size_t)(bw * TSEQ + q0 + wq * 16 + lr)) << 10)
                                     + h * 64 + ks * 32 + lk * 8);
    __builtin_amdgcn_sched_barrier(0);

    const int qloc = wq * 16 + lr;        // local q row (QK output col / sP row)
    const int qcol = q0 + qloc;           // global q for this lane's S column
    const float* rabq = rab + ((size_t)h * TSEQ + qcol) * TSEQ + lk * 4;

    f32x4 acc[4] = {};

    // 4 gl_lds per thread: K and Vt for both batches, 1 chunk each (512 chunks/tile)
    #define STAGE(buf, kt_) do {                                                      \
        int k0s = (kt_) * 64;                                                         \
        int rr = tid >> 3, kc = tid & 7;                                              \
        int kcs = kc ^ (rr & 7);                                                      \
        gl_lds16(Kb + (((size_t)(k0s + rr)) << 10) + h * 64 + kcs * 8,                \
                 sK[buf][0] + tid * 8);                                               \
        gl_lds16(Kb + (((size_t)(TSEQ + k0s + rr)) << 10) + h * 64 + kcs * 8,         \
                 sK[buf][1] + tid * 8);                                               \
        gl_lds16(Vt + (((size_t)(h * 64 + rr)) << 12) + k0s + kcs * 8,                \
                 sVt[buf][0] + tid * 8);                                              \
        gl_lds16(Vt + (((size_t)(h * 64 + rr)) << 12) + TSEQ + k0s + kcs * 8,         \
                 sVt[buf][1] + tid * 8);                                              \
    } while (0)

    float4 rv0[4], rv1[4];

    STAGE(0, 0);
    __builtin_amdgcn_sched_barrier(0);
    #pragma unroll
    for (int nt = 0; nt < 4; ++nt)
        rv0[nt] = *(const float4*)(rabq + nt * 16);
    __builtin_amdgcn_sched_barrier(0);
    // drain qreg (2) + stage (4); keep the 4 rab float4 loads in flight
    asm volatile("s_waitcnt vmcnt(4)" ::: "memory");
    __builtin_amdgcn_s_barrier();

    #define BODY(KT, BUFC, RVC, RVN) do {                                             \
        const int k0 = (KT) * 64;                                                     \
        const bool have_next = (KT) < qt;                                             \
        if (have_next) STAGE((BUFC) ^ 1, (KT) + 1);                                   \
        __builtin_amdgcn_sched_barrier(0);                                            \
        if (have_next) {                                                              \
            _Pragma("unroll")                                                         \
            for (int nt = 0; nt < 4; ++nt)                                            \
                RVN[nt] = *(const float4*)(rabq + k0 + 64 + nt * 16);                 \
        }                                                                             \
        __builtin_amdgcn_sched_barrier(0);                                            \
        f32x4 s[4];                                                                   \
        _Pragma("unroll")                                                             \
        for (int nt = 0; nt < 4; ++nt) {                                              \
            s[nt][0] = RVC[nt].x; s[nt][1] = RVC[nt].y;                               \
            s[nt][2] = RVC[nt].z; s[nt][3] = RVC[nt].w;                               \
        }                                                                             \
        __builtin_amdgcn_s_setprio(1);                                                \
        _Pragma("unroll")                                                             \
        for (int ks = 0; ks < 2; ++ks) {                                              \
            _Pragma("unroll")                                                         \
            for (int nt = 0; nt < 4; ++nt)                                            \
                s[nt] = __builtin_amdgcn_mfma_f32_16x16x32_bf16(                      \
                    rd_swz(sK[BUFC][bw], nt * 16 + lr, ks * 4 + lk), qreg[ks],        \
                    s[nt], 0, 0, 0);                                                  \
        }                                                                             \
        __builtin_amdgcn_s_setprio(0);                                                \
        char* pb = (char*)sP[bw];                                                     \
        char* paddr = pb + qloc * 128 + ((lk & 1) * 8);                               \
        if (have_next) {                                                              \
            _Pragma("unroll")                                                         \
            for (int nt = 0; nt < 4; ++nt) {                                          \
                unsigned int p01 = pack_bf16(silu_f(s[nt][0]), silu_f(s[nt][1]));     \
                unsigned int p23 = pack_bf16(silu_f(s[nt][2]), silu_f(s[nt][3]));     \
                const int chunk = nt * 2 + (lk >> 1);                                 \
                *(uint2*)(paddr + ((chunk ^ (qloc & 7)) << 4)) = make_uint2(p01, p23);\
            }                                                                         \
        } else {                                                                      \
            _Pragma("unroll")                                                         \
            for (int nt = 0; nt < 4; ++nt) {                                          \
                const int kb = k0 + nt * 16 + lk * 4;                                 \
                float a0 = (kb + 0 <= qcol) ? silu_f(s[nt][0]) : 0.f;                 \
                float a1 = (kb + 1 <= qcol) ? silu_f(s[nt][1]) : 0.f;                 \
                float a2 = (kb + 2 <= qcol) ? silu_f(s[nt][2]) : 0.f;                 \
                float a3 = (kb + 3 <= qcol) ? silu_f(s[nt][3]) : 0.f;                 \
                unsigned int p01 = pack_bf16(a0, a1);                                 \
                unsigned int p23 = pack_bf16(a2, a3);                                 \
                const int chunk = nt * 2 + (lk >> 1);                                 \
                *(uint2*)(paddr + ((chunk ^ (qloc & 7)) << 4)) = make_uint2(p01, p23);\
            }                                                                         \
        }                                                                             \
        __builtin_amdgcn_s_setprio(1);                                                \
        _Pragma("unroll")                                                             \
        for (int ks = 0; ks < 2; ++ks) {                                              \
            short8 ap = rd_swz(sP[bw], qloc, ks * 4 + lk);                            \
            _Pragma("unroll")                                                         \
            for (int dt = 0; dt < 4; ++dt)                                            \
                acc[dt] = __builtin_amdgcn_mfma_f32_16x16x32_bf16(                    \
                    ap, rd_swz(sVt[BUFC][bw], dt * 16 + lr, ks * 4 + lk),             \
                    acc[dt], 0, 0, 0);                                                \
        }                                                                             \
        __builtin_amdgcn_s_setprio(0);                                                \
        if (have_next) {                                                              \
            asm volatile("s_waitcnt vmcnt(4)" ::: "memory");                          \
            __builtin_amdgcn_s_barrier();                                             \
        }                                                                             \
    } while (0)

    for (int kt = 0; kt <= qt; kt += 2) {
        BODY(kt, 0, rv0, rv1);
        if (kt + 1 <= qt) BODY(kt + 1, 1, rv1, rv0);
    }
    #undef BODY
    #undef STAGE

    #pragma unroll
    for (int dt = 0; dt < 4; ++dt)
        #pragma unroll
        for (int j = 0; j < 4; ++j)
            AV[(((size_t)(bw * TSEQ + q0 + wq * 16 + lk * 4 + j)) << 10)
               + h * 64 + dt * 16 + lr] = f2bf(acc[dt][j]);
}

// ---------------- LayerNorm(AV) * U -> z (bf16) ----------------
// AV rows are scaled by c=(q+1) vs reference; LN(c*x) with eps*c^2 == LN(x) exactly.
__global__ __launch_bounds__(256) void k_ln(const unsigned short* __restrict__ AV,
                                            const unsigned short* __restrict__ U,
                                            const float* __restrict__ lnw,
                                            const float* __restrict__ lnb,
                                            unsigned short* __restrict__ z) {
    __shared__ float red[8];
    const int row = blockIdx.x, tid = threadIdx.x;
    const float c = (float)((row & (TSEQ - 1)) + 1);
    const float eps = 1e-5f * c * c;
    union { unsigned short s[4]; uint2 u; } a;
    a.u = ((const uint2*)(AV + ((size_t)row << 10)))[tid];
    float v[4];
    #pragma unroll
    for (int i = 0; i < 4; ++i) v[i] = bf2f(a.s[i]);
    float s = v[0] + v[1] + v[2] + v[3];
    float s2 = v[0] * v[0] + v[1] * v[1] + v[2] * v[2] + v[3] * v[3];
    #pragma unroll
    for (int o = 32; o > 0; o >>= 1) { s += __shfl_xor(s, o); s2 += __shfl_xor(s2, o); }
    const int w = tid >> 6;
    if ((tid & 63) == 0) { red[w] = s; red[4 + w] = s2; }
    __syncthreads();
    s = red[0] + red[1] + red[2] + red[3];
    s2 = red[4] + red[5] + red[6] + red[7];
    const float mu = s * (1.f / 1024.f);
    const float var = s2 * (1.f / 1024.f) - mu * mu;
    const float rstd = rsqrtf(var + eps);
    union { unsigned short s[4]; uint2 u; } uu;
    uu.u = ((const uint2*)(U + ((size_t)row << 10)))[tid];
    float4 lw = ((const float4*)lnw)[tid];
    float4 lb = ((const float4*)lnb)[tid];
    union { unsigned short o[4]; uint2 u; } ov;
    ov.o[0] = f2bf(((v[0] - mu) * rstd * lw.x + lb.x) * bf2f(uu.s[0]));
    ov.o[1] = f2bf(((v[1] - mu) * rstd * lw.y + lb.y) * bf2f(uu.s[1]));
    ov.o[2] = f2bf(((v[2] - mu) * rstd * lw.z + lb.z) * bf2f(uu.s[2]));
    ov.o[3] = f2bf(((v[3] - mu) * rstd * lw.w + lb.w) * bf2f(uu.s[3]));
    ((uint2*)z)[((size_t)row << 8) + tid] = ov.u;
}

extern "C" void kernel_launch(void* const* d_in, const int* in_sizes, int n_in,
                              void* d_out, int out_size, void* d_ws, size_t ws_size,
                              hipStream_t stream) {
    const float* x     = (const float*)d_in[0];
    const float* rab   = (const float*)d_in[2];
    const float* W_in  = (const float*)d_in[3];
    const float* b_in  = (const float*)d_in[4];
    const float* W_out = (const float*)d_in[5];
    const float* b_out = (const float*)d_in[6];
    const float* ln_w  = (const float*)d_in[7];
    const float* ln_b  = (const float*)d_in[8];
    float* y = (float*)d_out;

    char* ws = (char*)d_ws;
    size_t off = 0;
    auto alloc = [&](size_t bytes) -> void* {
        void* p = ws + off;
        off += (bytes + 255) & ~(size_t)255;
        return p;
    };
    unsigned short* WinT  = (unsigned short*)alloc((size_t)4096 * 1024 * 2);
    unsigned short* WoutT = (unsigned short*)alloc((size_t)1024 * 1024 * 2);
    unsigned short* xb    = (unsigned short*)alloc((size_t)MROWS * DIM * 2);
    unsigned short* Ubuf  = (unsigned short*)alloc((size_t)MROWS * DIM * 2);
    unsigned short* Qb    = (unsigned short*)alloc((size_t)MROWS * DIM * 2);
    unsigned short* Kb    = (unsigned short*)alloc((size_t)MROWS * DIM * 2);
    unsigned short* Vtb   = (unsigned short*)alloc((size_t)DIM * MROWS * 2);
    unsigned short* AV    = (unsigned short*)alloc((size_t)MROWS * DIM * 2);
    unsigned short* z     = (unsigned short*)alloc((size_t)MROWS * DIM * 2);

    // merged prep: x->bf16 + both weight transposes
    k_prep<<<dim3(9216), dim3(256), 0, stream>>>(x, xb, W_in, WinT, W_out, WoutT);
    // GEMM1 (256^2 4-phase, counted vmcnt): h = silu(x @ W_in + b_in) -> U, V^T, Q(*alpha), K
    k_gemm1_256<<<dim3(16, 16), dim3(512), 0, stream>>>(xb, WinT, b_in, Ubuf, Vtb, Qb, Kb);
    // attention (paired batches, 8 waves, 2 blocks/CU; AV unscaled, bf16)
    k_attn<<<dim3(512), dim3(512), 0, stream>>>(Qb, Kb, Vtb, rab, AV);
    // LN * U (eps compensated per-row)
    k_ln<<<dim3(MROWS), dim3(256), 0, stream>>>(AV, Ubuf, ln_w, ln_b, z);
    // GEMM2 (128^2 BK=64 2-phase, counted vmcnt): y = z @ W_out + b_out
    k_gemm2<<<dim3(32, 8), dim3(256), 0, stream>>>(z, WoutT, b_out, y);
}

// Round 15
// 156.374 us; speedup vs baseline: 1.4047x; 1.0839x over previous
//
#include <hip/hip_runtime.h>
#include <hip/hip_bf16.h>

// Problem constants
#define BATCH 2
#define TSEQ 2048
#define DIM 1024
#define NH 16
#define HDIM 64
#define MROWS (BATCH * TSEQ)   // 4096

typedef __attribute__((ext_vector_type(4))) float f32x4;
typedef __attribute__((ext_vector_type(8))) short short8;

__device__ __forceinline__ unsigned short f2bf(float f) {
    union { float f; unsigned int u; } x; x.f = f;
    unsigned int r = x.u + 0x7fffu + ((x.u >> 16) & 1u);
    return (unsigned short)(r >> 16);
}

__device__ __forceinline__ float bf2f(unsigned short s) {
    union { unsigned int u; float f; } t; t.u = (unsigned int)s << 16;
    return t.f;
}

__device__ __forceinline__ float silu_f(float v) {
    return v * __builtin_amdgcn_rcpf(1.f + __expf(-v));
}

__device__ __forceinline__ unsigned int pack_bf16(float lo, float hi) {
    union { __hip_bfloat162 h; unsigned int u; } r;
    r.h = __float22bfloat162_rn(float2{lo, hi});
    return r.u;
}

__device__ __forceinline__ void gl_lds16(const void* g, void* l) {
    __builtin_amdgcn_global_load_lds(
        (const __attribute__((address_space(1))) void*)g,
        (__attribute__((address_space(3))) void*)l, 16, 0, 0);
}

// swizzled LDS 16B-chunk read: row stride 128B, chunk index XOR (row&7)
__device__ __forceinline__ short8 rd_swz(const unsigned short* base, int row, int chunk) {
    const char* b = (const char*)base;
    return *(const short8*)(b + row * 128 + (((chunk ^ (row & 7)) << 4)));
}

// ---------------- merged prep: convert x->bf16; transpose W_in, W_out ----------------
__device__ __forceinline__ void transpose32(const float* __restrict__ in,
                                            unsigned short* __restrict__ out,
                                            int R, int C, int bx, int by, int tid) {
    __shared__ float tile[32][33];
    int tx = tid & 31, ty = tid >> 5;   // (32,8)
    int c0 = bx * 32, r0 = by * 32;
    #pragma unroll
    for (int i = 0; i < 32; i += 8)
        tile[ty + i][tx] = in[(size_t)(r0 + ty + i) * C + c0 + tx];
    __syncthreads();
    #pragma unroll
    for (int i = 0; i < 32; i += 8)
        out[(size_t)(c0 + ty + i) * R + r0 + tx] = f2bf(tile[tx][ty + i]);
}

__global__ __launch_bounds__(256) void k_prep(const float* __restrict__ x,
                                              unsigned short* __restrict__ xb,
                                              const float* __restrict__ W_in,
                                              unsigned short* __restrict__ WinT,
                                              const float* __restrict__ W_out,
                                              unsigned short* __restrict__ WoutT) {
    const int b = blockIdx.x, tid = threadIdx.x;
    if (b < 4096) {
        int i = b * 256 + tid;
        float4 v = ((const float4*)x)[i];
        union { unsigned short s[4]; uint2 u; } o;
        o.s[0] = f2bf(v.x); o.s[1] = f2bf(v.y); o.s[2] = f2bf(v.z); o.s[3] = f2bf(v.w);
        ((uint2*)xb)[i] = o.u;
    } else if (b < 8192) {
        int bb = b - 4096;             // 128 x 32
        transpose32(W_in, WinT, 1024, 4096, bb & 127, bb >> 7, tid);
    } else {
        int bb = b - 8192;             // 32 x 32
        transpose32(W_out, WoutT, 1024, 1024, bb & 31, bb >> 5, tid);
    }
}

// ---------------- GEMM1: 256x256 tile, BK=64, 8 waves, 4-phase, counted vmcnt ----------------
__device__ __forceinline__ void stage256o(const unsigned short* __restrict__ A,
                                          const unsigned short* __restrict__ Bt,
                                          int row0, int col0, int k0,
                                          unsigned short* sAbuf, unsigned short* sBbuf,
                                          int tid) {
    #pragma unroll
    for (int q = 0; q < 4; ++q) {
        int c = tid + 512 * q;
        int rr = c >> 3;
        int kcs = (c & 7) ^ (rr & 7);
        gl_lds16(Bt + (size_t)(col0 + rr) * 1024 + k0 + kcs * 8, sBbuf + c * 8);
    }
    __builtin_amdgcn_sched_barrier(0);
    #pragma unroll
    for (int p = 0; p < 4; ++p) {
        int c = (tid < 256) ? (256 * p + tid) : (1024 + 256 * p + (tid - 256));
        int rr = c >> 3;
        int kcs = (c & 7) ^ (rr & 7);
        gl_lds16(A + (size_t)(row0 + rr) * 1024 + k0 + kcs * 8, sAbuf + c * 8);
        __builtin_amdgcn_sched_barrier(0);
    }
}

__global__ __launch_bounds__(512, 2) void k_gemm1_256(
    const unsigned short* __restrict__ A, const unsigned short* __restrict__ Bt,
    const float* __restrict__ bias,
    unsigned short* __restrict__ outU, unsigned short* __restrict__ outVt,
    unsigned short* __restrict__ outQ, unsigned short* __restrict__ outK)
{
    __shared__ __align__(16) unsigned short sA[2][256 * 64];
    __shared__ __align__(16) unsigned short sB[2][256 * 64];   // 128 KiB total

    const int tid = threadIdx.x;           // 0..511
    const int lane = tid & 63, wid = tid >> 6;
    const int lr = lane & 15, lk = lane >> 4;
    const int wm = wid >> 2, wn = wid & 3; // 2M x 4N wave grid
    const int bm = blockIdx.x, bn = blockIdx.y;
    const int row0 = bm * 256, col0 = bn * 256;

    f32x4 acc[8][4] = {};

    stage256o(A, Bt, row0, col0, 0, sA[0], sB[0], tid);
    asm volatile("s_waitcnt vmcnt(0)" ::: "memory");
    __builtin_amdgcn_s_barrier();
    __builtin_amdgcn_sched_barrier(0);

    int cur = 0;
    for (int kt = 0; kt < 15; ++kt) {
        stage256o(A, Bt, row0, col0, (kt + 1) * 64, sA[cur ^ 1], sB[cur ^ 1], tid);
        short8 bf[2][4];
        #pragma unroll
        for (int kk = 0; kk < 2; ++kk)
            #pragma unroll
            for (int n = 0; n < 4; ++n)
                bf[kk][n] = rd_swz(sB[cur], wn * 64 + n * 16 + lr, kk * 4 + lk);

        #pragma unroll
        for (int ph = 0; ph < 4; ++ph) {
            short8 af[2][2];
            #pragma unroll
            for (int mm = 0; mm < 2; ++mm)
                #pragma unroll
                for (int kk = 0; kk < 2; ++kk)
                    af[mm][kk] = rd_swz(sA[cur], wm * 128 + (ph * 2 + mm) * 16 + lr, kk * 4 + lk);
            __builtin_amdgcn_s_barrier();
            __builtin_amdgcn_s_setprio(1);
            #pragma unroll
            for (int mm = 0; mm < 2; ++mm)
                #pragma unroll
                for (int n = 0; n < 4; ++n)
                    #pragma unroll
                    for (int kk = 0; kk < 2; ++kk)
                        acc[ph * 2 + mm][n] = __builtin_amdgcn_mfma_f32_16x16x32_bf16(
                            af[mm][kk], bf[kk][n], acc[ph * 2 + mm][n], 0, 0, 0);
            __builtin_amdgcn_s_setprio(0);
            // counted ladder: wait only for the chunks the NEXT phase reads
            if (ph == 0)      asm volatile("s_waitcnt vmcnt(10)" ::: "memory");
            else if (ph == 1) asm volatile("s_waitcnt vmcnt(9)" ::: "memory");
            else if (ph == 2) asm volatile("s_waitcnt vmcnt(8)" ::: "memory");
            else              asm volatile("s_waitcnt vmcnt(3)" ::: "memory");
            __builtin_amdgcn_s_barrier();
        }
        __builtin_amdgcn_sched_barrier(0);
        cur ^= 1;
    }

    // last K-tile: ladder {2,1,0}
    {
        short8 bf[2][4];
        #pragma unroll
        for (int kk = 0; kk < 2; ++kk)
            #pragma unroll
            for (int n = 0; n < 4; ++n)
                bf[kk][n] = rd_swz(sB[cur], wn * 64 + n * 16 + lr, kk * 4 + lk);
        #pragma unroll
        for (int ph = 0; ph < 4; ++ph) {
            short8 af[2][2];
            #pragma unroll
            for (int mm = 0; mm < 2; ++mm)
                #pragma unroll
                for (int kk = 0; kk < 2; ++kk)
                    af[mm][kk] = rd_swz(sA[cur], wm * 128 + (ph * 2 + mm) * 16 + lr, kk * 4 + lk);
            __builtin_amdgcn_s_barrier();
            __builtin_amdgcn_s_setprio(1);
            #pragma unroll
            for (int mm = 0; mm < 2; ++mm)
                #pragma unroll
                for (int n = 0; n < 4; ++n)
                    #pragma unroll
                    for (int kk = 0; kk < 2; ++kk)
                        acc[ph * 2 + mm][n] = __builtin_amdgcn_mfma_f32_16x16x32_bf16(
                            af[mm][kk], bf[kk][n], acc[ph * 2 + mm][n], 0, 0, 0);
            __builtin_amdgcn_s_setprio(0);
            if (ph == 0)      { asm volatile("s_waitcnt vmcnt(2)" ::: "memory"); __builtin_amdgcn_s_barrier(); }
            else if (ph == 1) { asm volatile("s_waitcnt vmcnt(1)" ::: "memory"); __builtin_amdgcn_s_barrier(); }
            else if (ph == 2) { asm volatile("s_waitcnt vmcnt(0)" ::: "memory"); __builtin_amdgcn_s_barrier(); }
        }
    }

    // epilogue: whole block lies in one section
    const int sec = bn >> 2;
    #pragma unroll
    for (int n = 0; n < 4; ++n) {
        const int cg = col0 + wn * 64 + n * 16 + lr;
        const int cc = cg & 1023;
        const float bv = bias[cg];
        #pragma unroll
        for (int m = 0; m < 8; ++m) {
            const int rg0 = row0 + wm * 128 + m * 16 + lk * 4;
            float sv[4];
            #pragma unroll
            for (int j = 0; j < 4; ++j)
                sv[j] = silu_f(acc[m][n][j] + bv);
            if (sec == 0) {
                #pragma unroll
                for (int j = 0; j < 4; ++j)
                    outU[((size_t)(rg0 + j) << 10) + cc] = f2bf(sv[j]);
            } else if (sec == 1) {
                union { unsigned short s[4]; uint2 u; } pk;
                #pragma unroll
                for (int j = 0; j < 4; ++j) pk.s[j] = f2bf(sv[j]);
                *(uint2*)(outVt + ((size_t)cc << 12) + rg0) = pk.u;
            } else if (sec == 2) {
                #pragma unroll
                for (int j = 0; j < 4; ++j)
                    outQ[((size_t)(rg0 + j) << 10) + cc] = f2bf(sv[j] * 0.125f);
            } else {
                #pragma unroll
                for (int j = 0; j < 4; ++j)
                    outK[((size_t)(rg0 + j) << 10) + cc] = f2bf(sv[j]);
            }
        }
    }
}

// ---------------- GEMM2: 128x128 tile, BK=64, 4 waves, 2-phase, counted vmcnt ----------------
__device__ __forceinline__ void stage128o(const unsigned short* __restrict__ A,
                                          const unsigned short* __restrict__ Bt,
                                          int row0, int col0, int k0,
                                          unsigned short* sAbuf, unsigned short* sBbuf,
                                          int tid) {
    #pragma unroll
    for (int q = 0; q < 4; ++q) {
        int c = tid + 256 * q;
        int rr = c >> 3;
        int kcs = (c & 7) ^ (rr & 7);
        gl_lds16(Bt + (size_t)(col0 + rr) * 1024 + k0 + kcs * 8, sBbuf + c * 8);
    }
    __builtin_amdgcn_sched_barrier(0);
    {
        int c = tid;          int rr = c >> 3; int kcs = (c & 7) ^ (rr & 7);
        gl_lds16(A + (size_t)(row0 + rr) * 1024 + k0 + kcs * 8, sAbuf + c * 8);
        c = 512 + tid;        rr = c >> 3;     kcs = (c & 7) ^ (rr & 7);
        gl_lds16(A + (size_t)(row0 + rr) * 1024 + k0 + kcs * 8, sAbuf + c * 8);
    }
    __builtin_amdgcn_sched_barrier(0);
    {
        int c = 256 + tid;    int rr = c >> 3; int kcs = (c & 7) ^ (rr & 7);
        gl_lds16(A + (size_t)(row0 + rr) * 1024 + k0 + kcs * 8, sAbuf + c * 8);
        c = 768 + tid;        rr = c >> 3;     kcs = (c & 7) ^ (rr & 7);
        gl_lds16(A + (size_t)(row0 + rr) * 1024 + k0 + kcs * 8, sAbuf + c * 8);
    }
    __builtin_amdgcn_sched_barrier(0);
}

__global__ __launch_bounds__(256, 2) void k_gemm2(
    const unsigned short* __restrict__ A, const unsigned short* __restrict__ Bt,
    const float* __restrict__ bias, float* __restrict__ outY)
{
    __shared__ __align__(16) unsigned short sA[2][128 * 64];
    __shared__ __align__(16) unsigned short sB[2][128 * 64];   // 64 KiB total

    const int tid = threadIdx.x;           // 0..255
    const int lane = tid & 63, wid = tid >> 6;
    const int lr = lane & 15, lk = lane >> 4;
    const int wm = wid >> 1, wn = wid & 1; // 2M x 2N wave grid, 64x64 per wave
    const int bm = blockIdx.x, bn = blockIdx.y;
    const int row0 = bm * 128, col0 = bn * 128;

    f32x4 acc[4][4] = {};

    stage128o(A, Bt, row0, col0, 0, sA[0], sB[0], tid);
    asm volatile("s_waitcnt vmcnt(0)" ::: "memory");
    __builtin_amdgcn_s_barrier();
    __builtin_amdgcn_sched_barrier(0);

    int cur = 0;
    for (int kt = 0; kt < 15; ++kt) {
        stage128o(A, Bt, row0, col0, (kt + 1) * 64, sA[cur ^ 1], sB[cur ^ 1], tid);
        short8 bf[2][4];
        #pragma unroll
        for (int kk = 0; kk < 2; ++kk)
            #pragma unroll
            for (int n = 0; n < 4; ++n)
                bf[kk][n] = rd_swz(sB[cur], wn * 64 + n * 16 + lr, kk * 4 + lk);

        #pragma unroll
        for (int ph = 0; ph < 2; ++ph) {
            short8 af[2][2];
            #pragma unroll
            for (int mm = 0; mm < 2; ++mm)
                #pragma unroll
                for (int kk = 0; kk < 2; ++kk)
                    af[mm][kk] = rd_swz(sA[cur], wm * 64 + (ph * 2 + mm) * 16 + lr, kk * 4 + lk);
            __builtin_amdgcn_s_barrier();
            __builtin_amdgcn_s_setprio(1);
            #pragma unroll
            for (int mm = 0; mm < 2; ++mm)
                #pragma unroll
                for (int n = 0; n < 4; ++n)
                    #pragma unroll
                    for (int kk = 0; kk < 2; ++kk)
                        acc[ph * 2 + mm][n] = __builtin_amdgcn_mfma_f32_16x16x32_bf16(
                            af[mm][kk], bf[kk][n], acc[ph * 2 + mm][n], 0, 0, 0);
            __builtin_amdgcn_s_setprio(0);
            if (ph == 0) asm volatile("s_waitcnt vmcnt(10)" ::: "memory");
            else         asm volatile("s_waitcnt vmcnt(2)" ::: "memory");
            __builtin_amdgcn_s_barrier();
        }
        __builtin_amdgcn_sched_barrier(0);
        cur ^= 1;
    }

    // last K-tile
    {
        short8 bf[2][4];
        #pragma unroll
        for (int kk = 0; kk < 2; ++kk)
            #pragma unroll
            for (int n = 0; n < 4; ++n)
                bf[kk][n] = rd_swz(sB[cur], wn * 64 + n * 16 + lr, kk * 4 + lk);
        #pragma unroll
        for (int ph = 0; ph < 2; ++ph) {
            short8 af[2][2];
            #pragma unroll
            for (int mm = 0; mm < 2; ++mm)
                #pragma unroll
                for (int kk = 0; kk < 2; ++kk)
                    af[mm][kk] = rd_swz(sA[cur], wm * 64 + (ph * 2 + mm) * 16 + lr, kk * 4 + lk);
            __builtin_amdgcn_s_barrier();
            __builtin_amdgcn_s_setprio(1);
            #pragma unroll
            for (int mm = 0; mm < 2; ++mm)
                #pragma unroll
                for (int n = 0; n < 4; ++n)
                    #pragma unroll
                    for (int kk = 0; kk < 2; ++kk)
                        acc[ph * 2 + mm][n] = __builtin_amdgcn_mfma_f32_16x16x32_bf16(
                            af[mm][kk], bf[kk][n], acc[ph * 2 + mm][n], 0, 0, 0);
            __builtin_amdgcn_s_setprio(0);
            if (ph == 0) { asm volatile("s_waitcnt vmcnt(0)" ::: "memory"); __builtin_amdgcn_s_barrier(); }
        }
    }

    #pragma unroll
    for (int n = 0; n < 4; ++n) {
        const int cg = col0 + wn * 64 + n * 16 + lr;
        const float bv = bias[cg];
        #pragma unroll
        for (int m = 0; m < 4; ++m) {
            const int rg0 = row0 + wm * 64 + m * 16 + lk * 4;
            #pragma unroll
            for (int j = 0; j < 4; ++j)
                outY[(size_t)(rg0 + j) * 1024 + cg] = acc[m][n][j] + bv;
        }
    }
}

// ---------------- fused pointwise attention ----------------
// grid: 1024 blocks x 256 threads; QBLK=64 (4 waves x 16 rows), KVBLK=64.
// XCD-locality decode: xcd = bid&7 = h&7 -> each XCD serves 2 heads x 2 batches
// (2 MB of K/V, fits 4 MB L2). Per-CU qt set {c, 31-c, (c+16)%32, 31-(c+16)%32}
// sums to 66 iterations (balanced).
// SWAPPED QK^T (S[k][q]); rab via float4; P via cvt_pk + ds_write_b64.
// AV is UNSCALED (no 1/(q+1)); k_ln compensates exactly via eps scaling.
__global__ __launch_bounds__(256, 4) void k_attn(
    const unsigned short* __restrict__ Qb,
    const unsigned short* __restrict__ Kb,
    const unsigned short* __restrict__ Vt,   // [1024][4096] = V transposed
    const float* __restrict__ rab,
    unsigned short* __restrict__ AV)
{
    __shared__ __align__(16) unsigned short sK[2][64 * 64];
    __shared__ __align__(16) unsigned short sVt[2][64 * 64];
    __shared__ __align__(16) unsigned short sP[64 * 64];   // 40 KB total

    const int tid = threadIdx.x;
    const int lane = tid & 63;
    const int w = tid >> 6;        // 0..3
    const int lr = lane & 15;
    const int lk = lane >> 4;

    const int bid = blockIdx.x;            // [0,1024)
    const int xcd = bid & 7;
    const int j_ = bid >> 3;
    const int cc_ = j_ & 31;
    const int b4 = j_ >> 5;                // 0..3
    const int h = ((b4 & 1) << 3) | xcd;
    const int bb = b4 >> 1;
    const int cc2 = (b4 >= 2) ? ((cc_ + 16) & 31) : cc_;
    const int qt = (b4 & 1) ? (31 - cc2) : cc2;
    const int q0 = qt * 64;

    // Q fragments in registers (B-operand of swapped QK; rows q0 + w*16 + lr)
    short8 qreg[2];
    #pragma unroll
    for (int ks = 0; ks < 2; ++ks)
        qreg[ks] = *(const short8*)(Qb + (((size_t)(bb * TSEQ + q0 + w * 16 + lr)) << 10)
                                     + h * 64 + ks * 32 + lk * 8);
    __builtin_amdgcn_sched_barrier(0);

    const int qloc = w * 16 + lr;        // local q row (QK output col / sP row)
    const int qcol = q0 + qloc;          // global q for this lane's S column
    const float* rabq = rab + ((size_t)h * TSEQ + qcol) * TSEQ + lk * 4;

    f32x4 acc[4] = {};

    #define STAGE(buf, kt_) do {                                                      \
        int k0s = (kt_) * 64;                                                         \
        for (int c = tid; c < 512; c += 256) {                                        \
            int rr = c >> 3, kc = c & 7;                                              \
            int kcs = kc ^ (rr & 7);                                                  \
            gl_lds16(Kb + (((size_t)(bb * TSEQ + k0s + rr)) << 10) + h * 64 + kcs * 8,\
                     sK[buf] + c * 8);                                                \
            gl_lds16(Vt + (((size_t)(h * 64 + rr)) << 12) + bb * TSEQ + k0s + kcs * 8,\
                     sVt[buf] + c * 8);                                               \
        }                                                                             \
    } while (0)

    float4 rv0[4], rv1[4];

    STAGE(0, 0);
    __builtin_amdgcn_sched_barrier(0);
    #pragma unroll
    for (int nt = 0; nt < 4; ++nt)
        rv0[nt] = *(const float4*)(rabq + nt * 16);
    __builtin_amdgcn_sched_barrier(0);
    asm volatile("s_waitcnt vmcnt(4)" ::: "memory");
    __builtin_amdgcn_s_barrier();

    #define BODY(KT, BUFC, RVC, RVN) do {                                             \
        const int k0 = (KT) * 64;                                                     \
        const bool have_next = (KT) < qt;                                             \
        if (have_next) STAGE((BUFC) ^ 1, (KT) + 1);                                   \
        __builtin_amdgcn_sched_barrier(0);                                            \
        if (have_next) {                                                              \
            _Pragma("unroll")                                                         \
            for (int nt = 0; nt < 4; ++nt)                                            \
                RVN[nt] = *(const float4*)(rabq + k0 + 64 + nt * 16);                 \
        }                                                                             \
        __builtin_amdgcn_sched_barrier(0);                                            \
        f32x4 s[4];                                                                   \
        _Pragma("unroll")                                                             \
        for (int nt = 0; nt < 4; ++nt) {                                              \
            s[nt][0] = RVC[nt].x; s[nt][1] = RVC[nt].y;                               \
            s[nt][2] = RVC[nt].z; s[nt][3] = RVC[nt].w;                               \
        }                                                                             \
        __builtin_amdgcn_s_setprio(1);                                                \
        _Pragma("unroll")                                                             \
        for (int ks = 0; ks < 2; ++ks) {                                              \
            _Pragma("unroll")                                                         \
            for (int nt = 0; nt < 4; ++nt)                                            \
                s[nt] = __builtin_amdgcn_mfma_f32_16x16x32_bf16(                      \
                    rd_swz(sK[BUFC], nt * 16 + lr, ks * 4 + lk), qreg[ks], s[nt], 0, 0, 0); \
        }                                                                             \
        __builtin_amdgcn_s_setprio(0);                                                \
        char* pb = (char*)sP;                                                         \
        char* paddr = pb + qloc * 128 + ((lk & 1) * 8);                               \
        if (have_next) {                                                              \
            _Pragma("unroll")                                                         \
            for (int nt = 0; nt < 4; ++nt) {                                          \
                unsigned int p01 = pack_bf16(silu_f(s[nt][0]), silu_f(s[nt][1]));     \
                unsigned int p23 = pack_bf16(silu_f(s[nt][2]), silu_f(s[nt][3]));     \
                const int chunk = nt * 2 + (lk >> 1);                                 \
                *(uint2*)(paddr + ((chunk ^ (qloc & 7)) << 4)) = make_uint2(p01, p23);\
            }                                                                         \
        } else {                                                                      \
            _Pragma("unroll")                                                         \
            for (int nt = 0; nt < 4; ++nt) {                                          \
                const int kb = k0 + nt * 16 + lk * 4;                                 \
                float a0 = (kb + 0 <= qcol) ? silu_f(s[nt][0]) : 0.f;                 \
                float a1 = (kb + 1 <= qcol) ? silu_f(s[nt][1]) : 0.f;                 \
                float a2 = (kb + 2 <= qcol) ? silu_f(s[nt][2]) : 0.f;                 \
                float a3 = (kb + 3 <= qcol) ? silu_f(s[nt][3]) : 0.f;                 \
                unsigned int p01 = pack_bf16(a0, a1);                                 \
                unsigned int p23 = pack_bf16(a2, a3);                                 \
                const int chunk = nt * 2 + (lk >> 1);                                 \
                *(uint2*)(paddr + ((chunk ^ (qloc & 7)) << 4)) = make_uint2(p01, p23);\
            }                                                                         \
        }                                                                             \
        __builtin_amdgcn_s_setprio(1);                                                \
        _Pragma("unroll")                                                             \
        for (int ks = 0; ks < 2; ++ks) {                                              \
            short8 ap = rd_swz(sP, qloc, ks * 4 + lk);                                \
            _Pragma("unroll")                                                         \
            for (int dt = 0; dt < 4; ++dt)                                            \
                acc[dt] = __builtin_amdgcn_mfma_f32_16x16x32_bf16(                    \
                    ap, rd_swz(sVt[BUFC], dt * 16 + lr, ks * 4 + lk), acc[dt], 0, 0, 0); \
        }                                                                             \
        __builtin_amdgcn_s_setprio(0);                                                \
        if (have_next) {                                                              \
            asm volatile("s_waitcnt vmcnt(4)" ::: "memory");                          \
            __builtin_amdgcn_s_barrier();                                             \
        }                                                                             \
    } while (0)

    for (int kt = 0; kt <= qt; kt += 2) {
        BODY(kt, 0, rv0, rv1);
        if (kt + 1 <= qt) BODY(kt + 1, 1, rv1, rv0);
    }
    #undef BODY
    #undef STAGE

    #pragma unroll
    for (int dt = 0; dt < 4; ++dt)
        #pragma unroll
        for (int j = 0; j < 4; ++j)
            AV[(((size_t)(bb * TSEQ + q0 + w * 16 + lk * 4 + j)) << 10)
               + h * 64 + dt * 16 + lr] = f2bf(acc[dt][j]);
}

// ---------------- LayerNorm(AV) * U -> z (bf16) ----------------
// AV rows are scaled by c=(q+1) vs reference; LN(c*x) with eps*c^2 == LN(x) exactly.
__global__ __launch_bounds__(256) void k_ln(const unsigned short* __restrict__ AV,
                                            const unsigned short* __restrict__ U,
                                            const float* __restrict__ lnw,
                                            const float* __restrict__ lnb,
                                            unsigned short* __restrict__ z) {
    __shared__ float red[8];
    const int row = blockIdx.x, tid = threadIdx.x;
    const float c = (float)((row & (TSEQ - 1)) + 1);
    const float eps = 1e-5f * c * c;
    union { unsigned short s[4]; uint2 u; } a;
    a.u = ((const uint2*)(AV + ((size_t)row << 10)))[tid];
    float v[4];
    #pragma unroll
    for (int i = 0; i < 4; ++i) v[i] = bf2f(a.s[i]);
    float s = v[0] + v[1] + v[2] + v[3];
    float s2 = v[0] * v[0] + v[1] * v[1] + v[2] * v[2] + v[3] * v[3];
    #pragma unroll
    for (int o = 32; o > 0; o >>= 1) { s += __shfl_xor(s, o); s2 += __shfl_xor(s2, o); }
    const int w = tid >> 6;
    if ((tid & 63) == 0) { red[w] = s; red[4 + w] = s2; }
    __syncthreads();
    s = red[0] + red[1] + red[2] + red[3];
    s2 = red[4] + red[5] + red[6] + red[7];
    const float mu = s * (1.f / 1024.f);
    const float var = s2 * (1.f / 1024.f) - mu * mu;
    const float rstd = rsqrtf(var + eps);
    union { unsigned short s[4]; uint2 u; } uu;
    uu.u = ((const uint2*)(U + ((size_t)row << 10)))[tid];
    float4 lw = ((const float4*)lnw)[tid];
    float4 lb = ((const float4*)lnb)[tid];
    union { unsigned short o[4]; uint2 u; } ov;
    ov.o[0] = f2bf(((v[0] - mu) * rstd * lw.x + lb.x) * bf2f(uu.s[0]));
    ov.o[1] = f2bf(((v[1] - mu) * rstd * lw.y + lb.y) * bf2f(uu.s[1]));
    ov.o[2] = f2bf(((v[2] - mu) * rstd * lw.z + lb.z) * bf2f(uu.s[2]));
    ov.o[3] = f2bf(((v[3] - mu) * rstd * lw.w + lb.w) * bf2f(uu.s[3]));
    ((uint2*)z)[((size_t)row << 8) + tid] = ov.u;
}

extern "C" void kernel_launch(void* const* d_in, const int* in_sizes, int n_in,
                              void* d_out, int out_size, void* d_ws, size_t ws_size,
                              hipStream_t stream) {
    const float* x     = (const float*)d_in[0];
    const float* rab   = (const float*)d_in[2];
    const float* W_in  = (const float*)d_in[3];
    const float* b_in  = (const float*)d_in[4];
    const float* W_out = (const float*)d_in[5];
    const float* b_out = (const float*)d_in[6];
    const float* ln_w  = (const float*)d_in[7];
    const float* ln_b  = (const float*)d_in[8];
    float* y = (float*)d_out;

    char* ws = (char*)d_ws;
    size_t off = 0;
    auto alloc = [&](size_t bytes) -> void* {
        void* p = ws + off;
        off += (bytes + 255) & ~(size_t)255;
        return p;
    };
    unsigned short* WinT  = (unsigned short*)alloc((size_t)4096 * 1024 * 2);
    unsigned short* WoutT = (unsigned short*)alloc((size_t)1024 * 1024 * 2);
    unsigned short* xb    = (unsigned short*)alloc((size_t)MROWS * DIM * 2);
    unsigned short* Ubuf  = (unsigned short*)alloc((size_t)MROWS * DIM * 2);
    unsigned short* Qb    = (unsigned short*)alloc((size_t)MROWS * DIM * 2);
    unsigned short* Kb    = (unsigned short*)alloc((size_t)MROWS * DIM * 2);
    unsigned short* Vtb   = (unsigned short*)alloc((size_t)DIM * MROWS * 2);
    unsigned short* AV    = (unsigned short*)alloc((size_t)MROWS * DIM * 2);
    unsigned short* z     = (unsigned short*)alloc((size_t)MROWS * DIM * 2);

    // merged prep: x->bf16 + both weight transposes
    k_prep<<<dim3(9216), dim3(256), 0, stream>>>(x, xb, W_in, WinT, W_out, WoutT);
    // GEMM1 (256^2 4-phase, counted vmcnt): h = silu(x @ W_in + b_in) -> U, V^T, Q(*alpha), K
    k_gemm1_256<<<dim3(16, 16), dim3(512), 0, stream>>>(xb, WinT, b_in, Ubuf, Vtb, Qb, Kb);
    // attention (XCD-local heads; AV unscaled, bf16)
    k_attn<<<dim3(1024), dim3(256), 0, stream>>>(Qb, Kb, Vtb, rab, AV);
    // LN * U (eps compensated per-row)
    k_ln<<<dim3(MROWS), dim3(256), 0, stream>>>(AV, Ubuf, ln_w, ln_b, z);
    // GEMM2 (128^2 BK=64 2-phase, counted vmcnt): y = z @ W_out + b_out
    k_gemm2<<<dim3(32, 8), dim3(256), 0, stream>>>(z, WoutT, b_out, y);
}